// Round 4
// baseline (343.982 us; speedup 1.0000x reference)
//
#include <hip/hip_runtime.h>
#include <stdint.h>
#include <float.h>

typedef _Float16 f16x8 __attribute__((ext_vector_type(8)));  // 8 f16 (4 VGPRs)
typedef _Float16 f16x4 __attribute__((ext_vector_type(4)));
typedef float f32x4 __attribute__((ext_vector_type(4)));

#define D_DIM 256
#define K_CODES 8192
#define M_TOK 32768
#define MARGIN 0.08f

__device__ __forceinline__ void gload_lds16(const void* g, void* l) {
  __builtin_amdgcn_global_load_lds(
      (__attribute__((address_space(1))) void*)(uintptr_t)g,
      (__attribute__((address_space(3))) void*)l,
      16, 0, 0);
}

// ---------------------------------------------------------------------------
// Kernel 1: codebook fp32 -> f16 (RNE), emitted in per-tile MFMA FRAGMENT
// ORDER, + fp32 row norms.
// Tile = 64 codes x 256 k = 32 KB. Fragment f = kk*4+ct (kk=k/32, ct=col/16)
// is 1 KB; reader-lane lr holds codes n0+ct*16+(lr&15), k = kk*32+(lr>>4)*8..+8.
// So reads in vq_main are 64-lane contiguous 1 KB chunks: conflict-free, and
// staging is a pure linear copy.
// ---------------------------------------------------------------------------
__global__ __launch_bounds__(256) void split_cb(
    const float* __restrict__ cb, char* __restrict__ c_frag,
    float* __restrict__ c_norm) {
  const int w = threadIdx.x >> 6, l = threadIdx.x & 63;
  const int n = blockIdx.x * 4 + w;      // code row
  f32x4 v = *(const f32x4*)(cb + n * D_DIM + l * 4);  // k = 4l .. 4l+3
  f16x4 h;
  float ns = 0.f;
#pragma unroll
  for (int j = 0; j < 4; ++j) {
    float f = v[j];
    ns = fmaf(f, f, ns);
    h[j] = (_Float16)f;  // RNE
  }
  // fragment coordinates of this 8-byte chunk (k0 = 4l)
  const int kk = l >> 3;             // k0/32
  const int g = (l >> 1) & 3;        // (k0/8)&3  -> reader lane group
  const int tile = n >> 6, ct = (n >> 4) & 3, lrow = n & 15;
  const int off = tile * 32768 + (kk * 4 + ct) * 1024 + (g * 16 + lrow) * 16 +
                  (l & 1) * 8;
  *(f16x4*)(c_frag + off) = h;
#pragma unroll
  for (int m = 32; m > 0; m >>= 1) ns += __shfl_xor(ns, m);
  if (l == 0) c_norm[n] = ns;
}

// ---------------------------------------------------------------------------
// Kernel 2: MFMA distance + per-token top-2 (score,index).
// Grid 512 = 256 row-groups x 2 code-sets; 256 thr (4 waves), 2 blocks/CU.
// Wave owns 32 rows (x_h+x_l f16 in regs, 2-term: (x_h+x_l).c_h).
// LDS: dbuf 2 x 32 KB fragment-major tiles; ds_read = contiguous 1 KB/wave
// with immediate offsets (no swizzle, no addr VALU, no bank conflicts).
// Score = c_norm[n] - 2*(x_h+x_l).c_h     (x_norm dropped: row-constant)
// ---------------------------------------------------------------------------
__global__ __launch_bounds__(256, 2) void vq_main(
    const float* __restrict__ x, const char* __restrict__ c_frag,
    const float* __restrict__ c_norm,
    float* __restrict__ out_s1, float* __restrict__ out_s2,
    int* __restrict__ out_i1, int* __restrict__ out_i2) {
  __shared__ char smem[65536];
  const int t = threadIdx.x;
  const int w = t >> 6, l = t & 63;
  const int lrow = l & 15, lg = l >> 4;
  const int cs = blockIdx.x & 1;
  const int rg = blockIdx.x >> 1;
  const int row0 = rg * 128 + w * 32;
  const int tile0 = cs * 64;  // 64 tiles (4096 codes) per code-set

  // A fragments: 32 rows x 256 k, f16 hi+lo, in registers (128 VGPR).
  // mfma 16x16x32 A layout: lane holds row = l&15, k = (l>>4)*8 + j.
  f16x8 a_hi[2][8], a_lo[2][8];
#pragma unroll
  for (int rb = 0; rb < 2; ++rb) {
    const float* xr = x + (size_t)(row0 + rb * 16 + lrow) * D_DIM;
#pragma unroll
    for (int kk = 0; kk < 8; ++kk) {
      f32x4 p0 = *(const f32x4*)(xr + kk * 32 + lg * 8);
      f32x4 p1 = *(const f32x4*)(xr + kk * 32 + lg * 8 + 4);
      float v[8];
#pragma unroll
      for (int j = 0; j < 4; ++j) { v[j] = p0[j]; v[j + 4] = p1[j]; }
#pragma unroll
      for (int j = 0; j < 8; ++j) {
        _Float16 h = (_Float16)v[j];
        a_hi[rb][kk][j] = h;
        a_lo[rb][kk][j] = (_Float16)(v[j] - (float)h);
      }
    }
  }

  float bs1[2][4], bs2[2][4];
  int bi1[2][4], bi2[2][4];
#pragma unroll
  for (int rb = 0; rb < 2; ++rb)
#pragma unroll
    for (int j = 0; j < 4; ++j) {
      bs1[rb][j] = FLT_MAX; bs2[rb][j] = FLT_MAX;
      bi1[rb][j] = 0; bi2[rb][j] = 0;
    }

  // stage: pure linear 32 KB copy (fragment order already in global)
  auto stage = [&](char* buf, int tt) {
    const char* src = c_frag + (size_t)tt * 32768;
#pragma unroll
    for (int i = 0; i < 8; ++i)
      gload_lds16(src + i * 4096 + t * 16, buf + i * 4096 + w * 1024);
  };

  stage(smem, tile0);
  __syncthreads();

  const char* fb0 = smem + l * 16;
  const char* fb1 = smem + 32768 + l * 16;

  for (int it = 0; it < 64; ++it) {
    const int n0 = (tile0 + it) * 64;
    const char* fb = (it & 1) ? fb1 : fb0;
    if (it + 1 < 64) stage(smem + ((it + 1) & 1) * 32768, tile0 + it + 1);

    float cn[4];
#pragma unroll
    for (int ct = 0; ct < 4; ++ct) cn[ct] = c_norm[n0 + ct * 16 + lrow];

    f32x4 acc[2][4];
#pragma unroll
    for (int rb = 0; rb < 2; ++rb)
#pragma unroll
      for (int ct = 0; ct < 4; ++ct) { f32x4 z = {0.f, 0.f, 0.f, 0.f}; acc[rb][ct] = z; }

#pragma unroll
    for (int kk = 0; kk < 8; ++kk) {
      f16x8 bh[4];
#pragma unroll
      for (int ct = 0; ct < 4; ++ct)
        bh[ct] = *(const f16x8*)(fb + (kk * 4 + ct) * 1024);  // imm offset
      // 16 MFMAs; dependents on the same acc are 8 apart
#pragma unroll
      for (int ct = 0; ct < 4; ++ct)
#pragma unroll
        for (int rb = 0; rb < 2; ++rb)
          acc[rb][ct] = __builtin_amdgcn_mfma_f32_16x16x32_f16(a_hi[rb][kk], bh[ct], acc[rb][ct], 0, 0, 0);
#pragma unroll
      for (int ct = 0; ct < 4; ++ct)
#pragma unroll
        for (int rb = 0; rb < 2; ++rb)
          acc[rb][ct] = __builtin_amdgcn_mfma_f32_16x16x32_f16(a_lo[rb][kk], bh[ct], acc[rb][ct], 0, 0, 0);
    }

    // per-token: min over the 4 ct candidates (min-tree), then top-2 update.
    // C/D layout: col = l&15 (code), row = (l>>4)*4 + j (token).
    const int nb = n0 + lrow;
#pragma unroll
    for (int rb = 0; rb < 2; ++rb)
#pragma unroll
      for (int j = 0; j < 4; ++j) {
        float s0 = fmaf(-2.f, acc[rb][0][j], cn[0]);
        float s1 = fmaf(-2.f, acc[rb][1][j], cn[1]);
        float s2 = fmaf(-2.f, acc[rb][2][j], cn[2]);
        float s3 = fmaf(-2.f, acc[rb][3][j], cn[3]);
        float m01 = fminf(s0, s1); int i01 = (s1 < s0) ? 1 : 0;  // tie -> lower ct
        float m23 = fminf(s2, s3); int i23 = (s3 < s2) ? 3 : 2;
        float mm = fminf(m01, m23); int ic = (m23 < m01) ? i23 : i01;
        int n = nb + (ic << 4);
        bool lt1 = mm < bs1[rb][j];
        bool lt2 = mm < bs2[rb][j];
        bs2[rb][j] = lt1 ? bs1[rb][j] : (lt2 ? mm : bs2[rb][j]);
        bi2[rb][j] = lt1 ? bi1[rb][j] : (lt2 ? n : bi2[rb][j]);
        bs1[rb][j] = lt1 ? mm : bs1[rb][j];
        bi1[rb][j] = lt1 ? n : bi1[rb][j];
      }
    __syncthreads();  // buf reuse fence; drains this iter's prefetch (vmcnt)
  }

  // merge top-2 sets across the 16 lanes (lane bits 0..3) sharing each token
#pragma unroll
  for (int m = 8; m >= 1; m >>= 1) {
#pragma unroll
    for (int rb = 0; rb < 2; ++rb)
#pragma unroll
      for (int j = 0; j < 4; ++j) {
        float u1 = __shfl_xor(bs1[rb][j], m);
        float u2 = __shfl_xor(bs2[rb][j], m);
        int v1 = __shfl_xor(bi1[rb][j], m);
        int v2 = __shfl_xor(bi2[rb][j], m);
        bool take = (u1 < bs1[rb][j]) || (u1 == bs1[rb][j] && v1 < bi1[rb][j]);
        if (take) {
          bool oldFirst = (bs1[rb][j] < u2) || (bs1[rb][j] == u2 && bi1[rb][j] < v2);
          bs2[rb][j] = oldFirst ? bs1[rb][j] : u2;
          bi2[rb][j] = oldFirst ? bi1[rb][j] : v2;
          bs1[rb][j] = u1; bi1[rb][j] = v1;
        } else {
          bool rep = (u1 < bs2[rb][j]) || (u1 == bs2[rb][j] && v1 < bi2[rb][j]);
          bs2[rb][j] = rep ? u1 : bs2[rb][j];
          bi2[rb][j] = rep ? v1 : bi2[rb][j];
        }
      }
  }
  if (lrow == 0) {
#pragma unroll
    for (int rb = 0; rb < 2; ++rb)
#pragma unroll
      for (int j = 0; j < 4; ++j) {
        const int tok = row0 + rb * 16 + lg * 4 + j;
        const int o = cs * M_TOK + tok;
        out_s1[o] = bs1[rb][j];
        out_s2[o] = bs2[rb][j];
        out_i1[o] = bi1[rb][j];
        out_i2[o] = bi2[rb][j];
      }
  }
}

// ---------------------------------------------------------------------------
// Kernel 3: merge the 2 code-sets' top-2; if margin small, fp64-rescore all
// 4 candidates (protects argmin against f16 quantization noise).
// ---------------------------------------------------------------------------
__global__ __launch_bounds__(256) void vq_merge(
    const float* __restrict__ s1a, const float* __restrict__ s2a,
    const int* __restrict__ i1a, const int* __restrict__ i2a,
    const float* __restrict__ x, const float* __restrict__ cb,
    int* __restrict__ fidx) {
  const int tk = blockIdx.x * 256 + threadIdx.x;
  float csc[4]; int cid[4];
  csc[0] = s1a[tk];           cid[0] = i1a[tk];
  csc[1] = s2a[tk];           cid[1] = i2a[tk];
  csc[2] = s1a[M_TOK + tk];   cid[2] = i1a[M_TOK + tk];
  csc[3] = s2a[M_TOK + tk];   cid[3] = i2a[M_TOK + tk];
  float b1 = FLT_MAX, b2 = FLT_MAX;
  int j1 = 0;
#pragma unroll
  for (int c = 0; c < 4; ++c) {
    float s = csc[c]; int n = cid[c];
    bool t1 = (s < b1) || (s == b1 && n < j1);
    bool t2 = (s < b2);
    b2 = t1 ? b1 : (t2 ? s : b2);
    b1 = t1 ? s : b1;
    j1 = t1 ? n : j1;
  }
  int pick = j1;
  if (b2 - b1 < MARGIN) {
    const float* xr = x + (size_t)tk * D_DIM;
    double bd = DBL_MAX; int bj = INT32_MAX;
#pragma unroll
    for (int c = 0; c < 4; ++c) {
      const float* cp = cb + (size_t)cid[c] * D_DIM;
      double d = 0.0;
      for (int dd = 0; dd < D_DIM; ++dd) {
        double e = (double)xr[dd] - (double)cp[dd];
        d = fma(e, e, d);
      }
      if (d < bd || (d == bd && cid[c] < bj)) { bd = d; bj = cid[c]; }
    }
    pick = bj;
  }
  fidx[tk] = pick;
}

// ---------------------------------------------------------------------------
// Kernel 4: gather + STE expression mimic: out = x + (q - x) in fp32
// (bitwise-matches the reference when the index matches).
// ---------------------------------------------------------------------------
__global__ __launch_bounds__(256) void vq_gather(
    const int* __restrict__ idx, const float* __restrict__ cb,
    const float* __restrict__ x, float* __restrict__ out) {
  const int w = threadIdx.x >> 6, l = threadIdx.x & 63;
  const int tk = blockIdx.x * 4 + w;
  const int id = idx[tk];
  f32x4 q = *(const f32x4*)(cb + (size_t)id * D_DIM + l * 4);
  f32x4 xv = *(const f32x4*)(x + (size_t)tk * D_DIM + l * 4);
  f32x4 o;
#pragma unroll
  for (int j = 0; j < 4; ++j) o[j] = xv[j] + (q[j] - xv[j]);
  *(f32x4*)(out + (size_t)tk * D_DIM + l * 4) = o;
}

extern "C" void kernel_launch(void* const* d_in, const int* in_sizes, int n_in,
                              void* d_out, int out_size, void* d_ws, size_t ws_size,
                              hipStream_t stream) {
  const float* x = (const float*)d_in[0];    // [8,4096,256] fp32
  const float* cbk = (const float*)d_in[1];  // [8192,256] fp32
  float* out = (float*)d_out;                // [8,4096,256] fp32
  char* ws = (char*)d_ws;
  // ws: c_frag 4M | c_norm 32K (pad 64K) | s1 256K | s2 256K | i1 256K |
  //     i2 256K | fidx 128K   (total ~5.4 MB)
  char* c_frag = ws;
  float* c_norm = (float*)(ws + (4u << 20));
  char* cand = ws + (4u << 20) + (64u << 10);
  float* s1 = (float*)(cand);
  float* s2 = (float*)(cand + (256u << 10));
  int* i1 = (int*)(cand + (512u << 10));
  int* i2 = (int*)(cand + (768u << 10));
  int* fidx = (int*)(cand + (1024u << 10));

  split_cb<<<K_CODES / 4, 256, 0, stream>>>(cbk, c_frag, c_norm);
  vq_main<<<512, 256, 0, stream>>>(x, c_frag, c_norm, s1, s2, i1, i2);
  vq_merge<<<M_TOK / 256, 256, 0, stream>>>(s1, s2, i1, i2, x, cbk, fidx);
  vq_gather<<<M_TOK / 4, 256, 0, stream>>>(fidx, cbk, x, out);
}